// Round 1
// baseline (799.320 us; speedup 1.0000x reference)
//
#include <hip/hip_runtime.h>

#define S 2048
#define DM 2048
#define NH 16
#define DH 128

typedef __attribute__((ext_vector_type(8))) short short8;
typedef __attribute__((ext_vector_type(4))) float floatx4;
typedef unsigned short u16;
typedef unsigned int u32;

__device__ __forceinline__ u16 f2bf(float f) {
  union { float f; u32 u; } v; v.f = f;
  u32 r = v.u + 0x7fffu + ((v.u >> 16) & 1u);
  return (u16)(r >> 16);
}

__device__ __forceinline__ floatx4 mfma16(short8 a, short8 b, floatx4 c) {
  return __builtin_amdgcn_mfma_f32_16x16x32_bf16(a, b, c, 0, 0, 0);
}

// ---------- convert x (fp32 -> bf16), 4 elems/thread ----------
__global__ void conv_x_k(const float* __restrict__ x, u16* __restrict__ xb) {
  int gid = blockIdx.x * 256 + threadIdx.x;
  float4 v = ((const float4*)x)[gid];
  union { u16 u[4]; uint2 p; } o;
  o.u[0] = f2bf(v.x); o.u[1] = f2bf(v.y); o.u[2] = f2bf(v.z); o.u[3] = f2bf(v.w);
  ((uint2*)xb)[gid] = o.p;
}

// ---------- transpose+convert weights: Wt[n*2048+k] = bf16(W[k*2048+n]) ----------
__global__ void conv_w_k(const float* __restrict__ W0, const float* __restrict__ W1,
                         const float* __restrict__ W2, const float* __restrict__ W3,
                         u16* __restrict__ out) {
  __shared__ float tile[32][33];
  const float* W = blockIdx.z == 0 ? W0 : blockIdx.z == 1 ? W1 : blockIdx.z == 2 ? W2 : W3;
  u16* O = out + (size_t)blockIdx.z * DM * DM;
  int tx = threadIdx.x & 31, ty = threadIdx.x >> 5;
  int k0 = blockIdx.y * 32, n0 = blockIdx.x * 32;
#pragma unroll
  for (int j = 0; j < 4; j++)
    tile[ty + j * 8][tx] = W[(size_t)(k0 + ty + j * 8) * DM + n0 + tx];
  __syncthreads();
#pragma unroll
  for (int j = 0; j < 4; j++)
    O[(size_t)(n0 + ty + j * 8) * DM + k0 + tx] = f2bf(tile[tx][ty + j * 8]);
}

// ---------- 128x128 bf16 MFMA GEMM with fused epilogues ----------
// A: M x 2048 bf16 row-major. Bt: Wt (N rows x K cols) bf16.
// opmode 0 (grid.z=0,1,2): z=0 -> rope -> oQ[(b,h,s,dh)]; z=1 -> rope -> oK; z=2 -> oV transposed [(b,h,dh,s)]
// opmode 1: plain fp32 out (output projection)
__global__ __launch_bounds__(256, 2)
void gemm_k(const u16* __restrict__ A, const u16* __restrict__ Wt,
            u16* __restrict__ oQ, u16* __restrict__ oK, u16* __restrict__ oV,
            float* __restrict__ oO, const int* __restrict__ tp, int opmode)
{
  constexpr int LDK = 40;  // 32 + 8 pad: 16B-aligned rows, 2-way-max bank aliasing
  __shared__ u16 As[128 * LDK];
  __shared__ u16 Bs[128 * LDK];
  const int t = threadIdx.x;
  const int w = t >> 6, lane = t & 63;
  const int l16 = lane & 15, quad = lane >> 4;
  const int m0 = blockIdx.y * 128, n0 = blockIdx.x * 128;
  const int wm = (w >> 1) * 64, wn = (w & 1) * 64;
  const u16* Bt = Wt + (size_t)(opmode == 1 ? 3 : blockIdx.z) * DM * DM;

  floatx4 acc[4][4] = {};

  for (int k0 = 0; k0 < DM; k0 += 32) {
#pragma unroll
    for (int i = 0; i < 2; i++) {
      int idx = t + i * 256;
      int r = idx >> 2, c8 = (idx & 3) << 3;
      *(short8*)&As[r * LDK + c8] = *(const short8*)&A[(size_t)(m0 + r) * DM + k0 + c8];
      *(short8*)&Bs[r * LDK + c8] = *(const short8*)&Bt[(size_t)(n0 + r) * DM + k0 + c8];
    }
    __syncthreads();
    short8 af[4], bfr[4];
#pragma unroll
    for (int i = 0; i < 4; i++) af[i] = *(short8*)&As[(wm + i * 16 + l16) * LDK + quad * 8];
#pragma unroll
    for (int i = 0; i < 4; i++) bfr[i] = *(short8*)&Bs[(wn + i * 16 + l16) * LDK + quad * 8];
#pragma unroll
    for (int mi = 0; mi < 4; mi++)
#pragma unroll
      for (int ni = 0; ni < 4; ni++)
        acc[mi][ni] = mfma16(af[mi], bfr[ni], acc[mi][ni]);
    __syncthreads();
  }

  const int mode = (opmode == 1) ? 3 : ((int)blockIdx.z == 2 ? 2 : 0);
  if (mode == 3) {
#pragma unroll
    for (int mi = 0; mi < 4; mi++) {
      int m = m0 + wm + mi * 16 + quad * 4;
#pragma unroll
      for (int ni = 0; ni < 4; ni++) {
        int n = n0 + wn + ni * 16 + l16;
#pragma unroll
        for (int r = 0; r < 4; r++)
          oO[(size_t)(m + r) * DM + n] = acc[mi][ni][r];
      }
    }
  } else if (mode == 2) {
    // V transposed store: Vt[((b*NH+h)*DH + dh)*S + s], 4 consecutive s per lane -> 8B store
#pragma unroll
    for (int mi = 0; mi < 4; mi++) {
      int m = m0 + wm + mi * 16 + quad * 4;
      int b = m >> 11, s = m & (S - 1);
#pragma unroll
      for (int ni = 0; ni < 4; ni++) {
        int f = n0 + wn + ni * 16 + l16;
        int h = f >> 7, dh = f & (DH - 1);
        union { u16 u[4]; uint2 p; } pk;
#pragma unroll
        for (int r = 0; r < 4; r++) pk.u[r] = f2bf(acc[mi][ni][r]);
        *(uint2*)&oV[((size_t)(b * NH + h) * DH + dh) * S + s] = pk.p;
      }
    }
  } else {
    // RoPE fused: pair element lives in adjacent lane (dh LSB == lane LSB)
    u16* Out = ((int)blockIdx.z == 0) ? oQ : oK;
#pragma unroll
    for (int mi = 0; mi < 4; mi++) {
#pragma unroll
      for (int r = 0; r < 4; r++) {
        int m = m0 + wm + mi * 16 + quad * 4 + r;
        int b = m >> 11, s = m & (S - 1);
        int ps = tp[s];
#pragma unroll
        for (int ni = 0; ni < 4; ni++) {
          int f = n0 + wn + ni * 16 + l16;
          int h = f >> 7, dh = f & (DH - 1);
          float own = acc[mi][ni][r];
          float oth = __shfl_xor(own, 1, 64);
          float fr = __expf((float)(dh & ~1) * (-9.210340371976184f / 128.0f));
          float ang = (float)ps * fr;
          float sn, cs; __sincosf(ang, &sn, &cs);
          float res = (dh & 1) ? (oth * sn + own * cs) : (own * cs - oth * sn);
          Out[((size_t)(b * NH + h) * S + s) * DH + dh] = f2bf(res);
        }
      }
    }
  }
}

// ---------- causal flash attention ----------
// Q,K: (B*H, S, DH) bf16 rope'd. Vt: (B*H, DH, S) bf16. O: (B, S, NH*DH) bf16.
// block = 4 waves; wave w owns 16 q-rows; k-tiles of 32; per-wave private LDS for P relayout.
__global__ __launch_bounds__(256, 2)
void attn_k(const u16* __restrict__ Q, const u16* __restrict__ K,
            const u16* __restrict__ Vt, u16* __restrict__ O)
{
  __shared__ u16 P[4][16 * 40];
  const int t = threadIdx.x, w = t >> 6, lane = t & 63;
  const int l16 = lane & 15, quad = lane >> 4;
  const int bh = blockIdx.y, b = bh >> 4, h = bh & 15;
  const int qw = blockIdx.x * 64 + w * 16;
  const u16* Qb = Q + (size_t)bh * S * DH;
  const u16* Kb = K + (size_t)bh * S * DH;
  const u16* Vb = Vt + (size_t)bh * DH * S;

  short8 aq[4];
#pragma unroll
  for (int kc = 0; kc < 4; kc++)
    aq[kc] = *(const short8*)&Qb[(size_t)(qw + l16) * DH + kc * 32 + quad * 8];

  floatx4 o[8] = {};
  float mx[4], sm[4];
#pragma unroll
  for (int r = 0; r < 4; r++) { mx[r] = -3.0e38f; sm[r] = 0.0f; }

  const float SC = 0.08838834764831845f * 1.4426950408889634f;  // 1/sqrt(128)*log2(e)
  const int kend = qw + 16;
  for (int k0 = 0; k0 < kend; k0 += 32) {
    floatx4 sc[2] = {};
#pragma unroll
    for (int hh = 0; hh < 2; hh++) {
      const u16* Krow = &Kb[(size_t)(k0 + hh * 16 + l16) * DH + quad * 8];
#pragma unroll
      for (int kc = 0; kc < 4; kc++) {
        short8 bk = *(const short8*)&Krow[kc * 32];
        sc[hh] = mfma16(aq[kc], bk, sc[hh]);
      }
    }
    float p0[4], p1[4], al[4];
#pragma unroll
    for (int r = 0; r < 4; r++) {
      int row = qw + quad * 4 + r;
      float v0 = sc[0][r] * SC, v1 = sc[1][r] * SC;
      if (k0 + l16 > row) v0 = -3.0e38f;
      if (k0 + 16 + l16 > row) v1 = -3.0e38f;
      float tm = fmaxf(v0, v1);
#pragma unroll
      for (int off = 1; off < 16; off <<= 1) tm = fmaxf(tm, __shfl_xor(tm, off, 16));
      float nm = fmaxf(mx[r], tm);
      al[r] = exp2f(mx[r] - nm);
      mx[r] = nm;
      v0 = exp2f(v0 - nm); v1 = exp2f(v1 - nm);
      p0[r] = v0; p1[r] = v1;
      float ts = v0 + v1;
#pragma unroll
      for (int off = 1; off < 16; off <<= 1) ts += __shfl_xor(ts, off, 16);
      sm[r] = sm[r] * al[r] + ts;
    }
#pragma unroll
    for (int t8 = 0; t8 < 8; t8++)
#pragma unroll
      for (int r = 0; r < 4; r++) o[t8][r] *= al[r];
    // P: C-layout -> LDS -> A-layout (per-wave private, no barrier needed)
#pragma unroll
    for (int r = 0; r < 4; r++) {
      P[w][(quad * 4 + r) * 40 + l16] = f2bf(p0[r]);
      P[w][(quad * 4 + r) * 40 + 16 + l16] = f2bf(p1[r]);
    }
    asm volatile("s_waitcnt lgkmcnt(0)" ::: "memory");
    short8 pf = *(short8*)&P[w][l16 * 40 + quad * 8];
#pragma unroll
    for (int t8 = 0; t8 < 8; t8++) {
      short8 bv = *(const short8*)&Vb[(size_t)(t8 * 16 + l16) * S + k0 + quad * 8];
      o[t8] = mfma16(pf, bv, o[t8]);
    }
  }

  float inv[4];
#pragma unroll
  for (int r = 0; r < 4; r++) inv[r] = 1.0f / sm[r];
#pragma unroll
  for (int t8 = 0; t8 < 8; t8++)
#pragma unroll
    for (int r = 0; r < 4; r++) {
      int row = qw + quad * 4 + r;
      O[((size_t)(b * S + row)) * DM + h * DH + t8 * 16 + l16] = f2bf(o[t8][r] * inv[r]);
    }
}

extern "C" void kernel_launch(void* const* d_in, const int* in_sizes, int n_in,
                              void* d_out, int out_size, void* d_ws, size_t ws_size,
                              hipStream_t stream) {
  const float* x  = (const float*)d_in[0];
  const float* Wq = (const float*)d_in[1];
  const float* Wk = (const float*)d_in[2];
  const float* Wv = (const float*)d_in[3];
  const float* Wo = (const float*)d_in[4];
  const int*   tp = (const int*)d_in[5];

  char* ws = (char*)d_ws;
  u16* Wt = (u16*)ws;                                   // 4 * 2048*2048 bf16 = 32 MB
  u16* xb = (u16*)(ws + 33554432);                      // 16 MB
  u16* Qb = (u16*)(ws + 50331648);                      // 16 MB
  u16* Kb = (u16*)(ws + 67108864);                      // 16 MB
  u16* Vb = (u16*)(ws + 83886080);                      // 16 MB
  u16* Ob = (u16*)(ws + 100663296);                     // 16 MB

  conv_x_k<<<8192, 256, 0, stream>>>(x, xb);
  conv_w_k<<<dim3(64, 64, 4), 256, 0, stream>>>(Wq, Wk, Wv, Wo, Wt);
  gemm_k<<<dim3(16, 32, 3), 256, 0, stream>>>(xb, Wt, Qb, Kb, Vb, nullptr, tp, 0);
  attn_k<<<dim3(32, 32), 256, 0, stream>>>(Qb, Kb, Vb, Ob);
  gemm_k<<<dim3(16, 32, 1), 256, 0, stream>>>(Ob, Wt, nullptr, nullptr, nullptr,
                                              (float*)d_out, tp, 1);
}

// Round 2
// 616.117 us; speedup vs baseline: 1.2974x; 1.2974x over previous
//
#include <hip/hip_runtime.h>

#define S 2048
#define DM 2048
#define NH 16
#define DH 128

typedef __attribute__((ext_vector_type(8))) short short8;
typedef __attribute__((ext_vector_type(4))) float floatx4;
typedef unsigned short u16;
typedef unsigned int u32;

__device__ __forceinline__ u16 f2bf(float f) {
  union { float f; u32 u; } v; v.f = f;
  u32 r = v.u + 0x7fffu + ((v.u >> 16) & 1u);
  return (u16)(r >> 16);
}
__device__ __forceinline__ u32 pack2(float lo, float hi) {
  return (u32)f2bf(lo) | ((u32)f2bf(hi) << 16);
}

__device__ __forceinline__ floatx4 mfma16(short8 a, short8 b, floatx4 c) {
  return __builtin_amdgcn_mfma_f32_16x16x32_bf16(a, b, c, 0, 0, 0);
}

// ---------- convert x (fp32 -> bf16), 4 elems/thread ----------
__global__ void conv_x_k(const float* __restrict__ x, u16* __restrict__ xb) {
  int gid = blockIdx.x * 256 + threadIdx.x;
  float4 v = ((const float4*)x)[gid];
  union { u16 u[4]; uint2 p; } o;
  o.u[0] = f2bf(v.x); o.u[1] = f2bf(v.y); o.u[2] = f2bf(v.z); o.u[3] = f2bf(v.w);
  ((uint2*)xb)[gid] = o.p;
}

// ---------- transpose+convert weights: Wt[n*2048+k] = bf16(W[k*2048+n]) ----------
__global__ void conv_w_k(const float* __restrict__ W0, const float* __restrict__ W1,
                         const float* __restrict__ W2, const float* __restrict__ W3,
                         u16* __restrict__ out) {
  __shared__ float tile[32][33];
  const float* W = blockIdx.z == 0 ? W0 : blockIdx.z == 1 ? W1 : blockIdx.z == 2 ? W2 : W3;
  u16* O = out + (size_t)blockIdx.z * DM * DM;
  int tx = threadIdx.x & 31, ty = threadIdx.x >> 5;
  int k0 = blockIdx.y * 32, n0 = blockIdx.x * 32;
#pragma unroll
  for (int j = 0; j < 4; j++)
    tile[ty + j * 8][tx] = W[(size_t)(k0 + ty + j * 8) * DM + n0 + tx];
  __syncthreads();
#pragma unroll
  for (int j = 0; j < 4; j++)
    O[(size_t)(n0 + ty + j * 8) * DM + k0 + tx] = f2bf(tile[tx][ty + j * 8]);
}

// ---------- 128x128 bf16 MFMA GEMM with fused epilogues ----------
__global__ __launch_bounds__(256, 2)
void gemm_k(const u16* __restrict__ A, const u16* __restrict__ Wt,
            u16* __restrict__ oQ, u16* __restrict__ oK, u16* __restrict__ oV,
            float* __restrict__ oO, const int* __restrict__ tp, int opmode)
{
  constexpr int LDK = 40;
  __shared__ u16 As[128 * LDK];
  __shared__ u16 Bs[128 * LDK];
  const int t = threadIdx.x;
  const int w = t >> 6, lane = t & 63;
  const int l16 = lane & 15, quad = lane >> 4;
  const int m0 = blockIdx.y * 128, n0 = blockIdx.x * 128;
  const int wm = (w >> 1) * 64, wn = (w & 1) * 64;
  const u16* Bt = Wt + (size_t)(opmode == 1 ? 3 : blockIdx.z) * DM * DM;

  floatx4 acc[4][4] = {};

  for (int k0 = 0; k0 < DM; k0 += 32) {
#pragma unroll
    for (int i = 0; i < 2; i++) {
      int idx = t + i * 256;
      int r = idx >> 2, c8 = (idx & 3) << 3;
      *(short8*)&As[r * LDK + c8] = *(const short8*)&A[(size_t)(m0 + r) * DM + k0 + c8];
      *(short8*)&Bs[r * LDK + c8] = *(const short8*)&Bt[(size_t)(n0 + r) * DM + k0 + c8];
    }
    __syncthreads();
    short8 af[4], bfr[4];
#pragma unroll
    for (int i = 0; i < 4; i++) af[i] = *(short8*)&As[(wm + i * 16 + l16) * LDK + quad * 8];
#pragma unroll
    for (int i = 0; i < 4; i++) bfr[i] = *(short8*)&Bs[(wn + i * 16 + l16) * LDK + quad * 8];
#pragma unroll
    for (int mi = 0; mi < 4; mi++)
#pragma unroll
      for (int ni = 0; ni < 4; ni++)
        acc[mi][ni] = mfma16(af[mi], bfr[ni], acc[mi][ni]);
    __syncthreads();
  }

  const int mode = (opmode == 1) ? 3 : ((int)blockIdx.z == 2 ? 2 : 0);
  if (mode == 3) {
#pragma unroll
    for (int mi = 0; mi < 4; mi++) {
      int m = m0 + wm + mi * 16 + quad * 4;
#pragma unroll
      for (int ni = 0; ni < 4; ni++) {
        int n = n0 + wn + ni * 16 + l16;
#pragma unroll
        for (int r = 0; r < 4; r++)
          oO[(size_t)(m + r) * DM + n] = acc[mi][ni][r];
      }
    }
  } else if (mode == 2) {
#pragma unroll
    for (int mi = 0; mi < 4; mi++) {
      int m = m0 + wm + mi * 16 + quad * 4;
      int b = m >> 11, s = m & (S - 1);
#pragma unroll
      for (int ni = 0; ni < 4; ni++) {
        int f = n0 + wn + ni * 16 + l16;
        int h = f >> 7, dh = f & (DH - 1);
        union { u16 u[4]; uint2 p; } pk;
#pragma unroll
        for (int r = 0; r < 4; r++) pk.u[r] = f2bf(acc[mi][ni][r]);
        *(uint2*)&oV[((size_t)(b * NH + h) * DH + dh) * S + s] = pk.p;
      }
    }
  } else {
    // RoPE fused; for Q (z==0) also fold 1/sqrt(dk)*log2(e) into the value
    u16* Out = ((int)blockIdx.z == 0) ? oQ : oK;
    const float qs = ((int)blockIdx.z == 0) ? 0.12752780f : 1.0f;
#pragma unroll
    for (int mi = 0; mi < 4; mi++) {
#pragma unroll
      for (int r = 0; r < 4; r++) {
        int m = m0 + wm + mi * 16 + quad * 4 + r;
        int b = m >> 11, s = m & (S - 1);
        int ps = tp[s];
#pragma unroll
        for (int ni = 0; ni < 4; ni++) {
          int f = n0 + wn + ni * 16 + l16;
          int h = f >> 7, dh = f & (DH - 1);
          float own = acc[mi][ni][r];
          float oth = __shfl_xor(own, 1, 64);
          float fr = __expf((float)(dh & ~1) * (-9.210340371976184f / 128.0f));
          float ang = (float)ps * fr;
          float sn, cs; __sincosf(ang, &sn, &cs);
          float res = (dh & 1) ? (oth * sn + own * cs) : (own * cs - oth * sn);
          Out[((size_t)(b * NH + h) * S + s) * DH + dh] = f2bf(res * qs);
        }
      }
    }
  }
}

// ---------- causal flash attention, S^T orientation ----------
// Per wave: one 16-row q-tile; lane owns q = qt + (lane&15); k-tile 64.
// S^T = K·Q^T (A=K rows, B=Q^T) -> C-layout: col=l16=q, row=quad*4+r=key.
// PV as O^T = V^T·P^T (A=V^T from Vt layout, B=P^T via tiny LDS relayout).
// Balance: wave processes tile pair (j, 127-j) -> constant work per wave.
__global__ __launch_bounds__(256, 2)
void attn_k(const u16* __restrict__ Q, const u16* __restrict__ K,
            const u16* __restrict__ Vt, u16* __restrict__ O)
{
  __shared__ u16 P[4][16 * 72];  // per-wave 16 q-rows x 64 k-cols (+8 pad)
  const int t = threadIdx.x, w = t >> 6, lane = t & 63;
  const int l16 = lane & 15, quad = lane >> 4;
  const int bh = blockIdx.y, b = bh >> 4, h = bh & 15;
  const u16* Qb = Q + (size_t)bh * S * DH;
  const u16* Kb = K + (size_t)bh * S * DH;
  const u16* Vb = Vt + (size_t)bh * DH * S;
  u16* Pw = P[w];
  const int tidx = blockIdx.x * 4 + w;  // 0..63

#pragma unroll
  for (int half = 0; half < 2; half++) {
    const int qt = (half ? (127 - tidx) : tidx) * 16;
    // Q fragment = B-operand (Q^T): lane n=l16=q, k-chunk kc covers dh 32kc..+32
    short8 aq[4];
#pragma unroll
    for (int kc = 0; kc < 4; kc++)
      aq[kc] = *(const short8*)&Qb[(size_t)(qt + l16) * DH + kc * 32 + quad * 8];

    floatx4 o[8] = {};
    float m_ = -3.0e38f, l_ = 0.0f;

    for (int k0 = 0; k0 < qt + 16; k0 += 64) {
      // ---- QK^T (transposed): sc[hh] rows = keys k0+16hh+quad*4+r, col = q=l16
      floatx4 sc[4] = {};
#pragma unroll
      for (int hh = 0; hh < 4; hh++) {
        const u16* Krow = &Kb[(size_t)(k0 + hh * 16 + l16) * DH + quad * 8];
#pragma unroll
        for (int kc = 0; kc < 4; kc++) {
          short8 kf = *(const short8*)&Krow[kc * 32];
          sc[hh] = mfma16(kf, aq[kc], sc[hh]);
        }
      }
      // ---- causal mask (only tiles overlapping the diagonal)
      if (k0 + 64 > qt) {
#pragma unroll
        for (int hh = 0; hh < 4; hh++)
#pragma unroll
          for (int r = 0; r < 4; r++) {
            int j = k0 + hh * 16 + quad * 4 + r;
            if (j > qt + l16) sc[hh][r] = -3.0e38f;
          }
      }
      // ---- online softmax, per-lane scalar state (q = l16)
      float mloc = -3.0e38f;
#pragma unroll
      for (int hh = 0; hh < 4; hh++) {
        float a0 = fmaxf(sc[hh][0], sc[hh][1]);
        float a1 = fmaxf(sc[hh][2], sc[hh][3]);
        mloc = fmaxf(mloc, fmaxf(a0, a1));
      }
      mloc = fmaxf(mloc, __shfl_xor(mloc, 16, 64));
      mloc = fmaxf(mloc, __shfl_xor(mloc, 32, 64));
      float nm = fmaxf(m_, mloc);
      float al = __builtin_amdgcn_exp2f(m_ - nm);
      m_ = nm;
      float sloc = 0.0f;
      uint2 pk[4];
#pragma unroll
      for (int hh = 0; hh < 4; hh++) {
        float e0 = __builtin_amdgcn_exp2f(sc[hh][0] - nm);
        float e1 = __builtin_amdgcn_exp2f(sc[hh][1] - nm);
        float e2 = __builtin_amdgcn_exp2f(sc[hh][2] - nm);
        float e3 = __builtin_amdgcn_exp2f(sc[hh][3] - nm);
        sloc += (e0 + e1) + (e2 + e3);
        pk[hh].x = pack2(e0, e1);
        pk[hh].y = pack2(e2, e3);
      }
      float ts = sloc + __shfl_xor(sloc, 16, 64);
      ts += __shfl_xor(ts, 32, 64);
      l_ = l_ * al + ts;
#pragma unroll
      for (int t8 = 0; t8 < 8; t8++)
#pragma unroll
        for (int r = 0; r < 4; r++) o[t8][r] *= al;
      // ---- P^T relayout: row q=l16, cols 16hh+quad*4..+4 contiguous -> b64 writes
#pragma unroll
      for (int hh = 0; hh < 4; hh++)
        *(uint2*)&Pw[l16 * 72 + hh * 16 + quad * 4] = pk[hh];
      asm volatile("s_waitcnt lgkmcnt(0)" ::: "memory");
      // ---- PV: O^T += V^T · P^T
#pragma unroll
      for (int c = 0; c < 2; c++) {
        short8 pf = *(short8*)&Pw[l16 * 72 + c * 32 + quad * 8];
#pragma unroll
        for (int t8 = 0; t8 < 8; t8++) {
          short8 av = *(const short8*)&Vb[(size_t)(t8 * 16 + l16) * S + k0 + c * 32 + quad * 8];
          o[t8] = mfma16(av, pf, o[t8]);
        }
      }
    }
    // ---- epilogue: lane's q-row = qt+l16, dh = t8*16 + quad*4 + r
    float inv = __builtin_amdgcn_rcpf(l_);
#pragma unroll
    for (int t8 = 0; t8 < 8; t8++) {
      union { u16 u[4]; uint2 p; } pk;
#pragma unroll
      for (int r = 0; r < 4; r++) pk.u[r] = f2bf(o[t8][r] * inv);
      *(uint2*)&O[((size_t)(b * S + qt + l16)) * DM + h * DH + t8 * 16 + quad * 4] = pk.p;
    }
  }
}

extern "C" void kernel_launch(void* const* d_in, const int* in_sizes, int n_in,
                              void* d_out, int out_size, void* d_ws, size_t ws_size,
                              hipStream_t stream) {
  const float* x  = (const float*)d_in[0];
  const float* Wq = (const float*)d_in[1];
  const float* Wk = (const float*)d_in[2];
  const float* Wv = (const float*)d_in[3];
  const float* Wo = (const float*)d_in[4];
  const int*   tp = (const int*)d_in[5];

  char* ws = (char*)d_ws;
  u16* Wt = (u16*)ws;
  u16* xb = (u16*)(ws + 33554432);
  u16* Qb = (u16*)(ws + 50331648);
  u16* Kb = (u16*)(ws + 67108864);
  u16* Vb = (u16*)(ws + 83886080);
  u16* Ob = (u16*)(ws + 100663296);

  conv_x_k<<<8192, 256, 0, stream>>>(x, xb);
  conv_w_k<<<dim3(64, 64, 4), 256, 0, stream>>>(Wq, Wk, Wv, Wo, Wt);
  gemm_k<<<dim3(16, 32, 3), 256, 0, stream>>>(xb, Wt, Qb, Kb, Vb, nullptr, tp, 0);
  attn_k<<<dim3(16, 32), 256, 0, stream>>>(Qb, Kb, Vb, Ob);
  gemm_k<<<dim3(16, 32, 1), 256, 0, stream>>>(Ob, Wt, nullptr, nullptr, nullptr,
                                              (float*)d_out, tp, 1);
}

// Round 3
// 377.005 us; speedup vs baseline: 2.1202x; 1.6342x over previous
//
#include <hip/hip_runtime.h>

#define S 2048
#define DM 2048
#define NH 16
#define DH 128

typedef __attribute__((ext_vector_type(8))) short short8;
typedef __attribute__((ext_vector_type(4))) float floatx4;
typedef unsigned short u16;
typedef unsigned int u32;

__device__ __forceinline__ u16 f2bf(float f) {
  union { float f; u32 u; } v; v.f = f;
  u32 r = v.u + 0x7fffu + ((v.u >> 16) & 1u);
  return (u16)(r >> 16);
}
__device__ __forceinline__ u32 pack2(float lo, float hi) {
  return (u32)f2bf(lo) | ((u32)f2bf(hi) << 16);
}

__device__ __forceinline__ floatx4 mfma16(short8 a, short8 b, floatx4 c) {
  return __builtin_amdgcn_mfma_f32_16x16x32_bf16(a, b, c, 0, 0, 0);
}

// async global -> LDS, 16B per lane. LDS dest = wave-uniform base + lane*16.
__device__ __forceinline__ void async_cp16(const u16* g, u16* l) {
  __builtin_amdgcn_global_load_lds(
      (const __attribute__((address_space(1))) void*)g,
      (__attribute__((address_space(3))) void*)l, 16, 0, 0);
}

// ---------- convert x (fp32 -> bf16), 4 elems/thread ----------
__global__ void conv_x_k(const float* __restrict__ x, u16* __restrict__ xb) {
  int gid = blockIdx.x * 256 + threadIdx.x;
  float4 v = ((const float4*)x)[gid];
  union { u16 u[4]; uint2 p; } o;
  o.u[0] = f2bf(v.x); o.u[1] = f2bf(v.y); o.u[2] = f2bf(v.z); o.u[3] = f2bf(v.w);
  ((uint2*)xb)[gid] = o.p;
}

// ---------- transpose+convert weights: Wt[n*2048+k] = bf16(W[k*2048+n]) ----------
__global__ void conv_w_k(const float* __restrict__ W0, const float* __restrict__ W1,
                         const float* __restrict__ W2, const float* __restrict__ W3,
                         u16* __restrict__ out) {
  __shared__ float tile[32][33];
  const float* W = blockIdx.z == 0 ? W0 : blockIdx.z == 1 ? W1 : blockIdx.z == 2 ? W2 : W3;
  u16* O = out + (size_t)blockIdx.z * DM * DM;
  int tx = threadIdx.x & 31, ty = threadIdx.x >> 5;
  int k0 = blockIdx.y * 32, n0 = blockIdx.x * 32;
#pragma unroll
  for (int j = 0; j < 4; j++)
    tile[ty + j * 8][tx] = W[(size_t)(k0 + ty + j * 8) * DM + n0 + tx];
  __syncthreads();
#pragma unroll
  for (int j = 0; j < 4; j++)
    O[(size_t)(n0 + ty + j * 8) * DM + k0 + tx] = f2bf(tile[tx][ty + j * 8]);
}

// ---------- 128x128 bf16 MFMA GEMM, global_load_lds staging, swizzled LDS ----------
// LDS unit = 16B chunk. Tile row = 32 k = 4 units. chunk c of row r stored at
// unit r*4 + (c ^ ((r>>1)&3))  -> ds_read_b128 frag reads are 2-way (free).
__global__ __launch_bounds__(256, 2)
void gemm_k(const u16* __restrict__ A, const u16* __restrict__ Wt,
            u16* __restrict__ oQ, u16* __restrict__ oK, u16* __restrict__ oV,
            float* __restrict__ oO, const int* __restrict__ tp, int opmode)
{
  __shared__ u16 As[128 * 32];
  __shared__ u16 Bs[128 * 32];
  const int t = threadIdx.x;
  const int w = t >> 6, lane = t & 63;
  const int l16 = lane & 15, quad = lane >> 4;
  const int m0 = blockIdx.y * 128, n0 = blockIdx.x * 128;
  const int wm = (w >> 1) * 64, wn = (w & 1) * 64;
  const u16* Bt = Wt + (size_t)(opmode == 1 ? 3 : blockIdx.z) * DM * DM;

  // staging precompute: instr i covers units i*256 + t
  const u16* pA[2]; const u16* pB[2]; u16* lA[2]; u16* lB[2];
#pragma unroll
  for (int i = 0; i < 2; i++) {
    int unit = i * 256 + t;
    int row = unit >> 2, s = unit & 3;
    int c = s ^ ((row >> 1) & 3);
    pA[i] = A + (size_t)(m0 + row) * DM + c * 8;
    pB[i] = Bt + (size_t)(n0 + row) * DM + c * 8;
    lA[i] = &As[unit * 8];
    lB[i] = &Bs[unit * 8];
  }

  floatx4 acc[4][4] = {};

  for (int k0 = 0; k0 < DM; k0 += 32) {
#pragma unroll
    for (int i = 0; i < 2; i++) {
      async_cp16(pA[i] + k0, lA[i]);
      async_cp16(pB[i] + k0, lB[i]);
    }
    __syncthreads();
    short8 af[4], bfr[4];
#pragma unroll
    for (int i = 0; i < 4; i++) {
      int row = wm + i * 16 + l16;
      af[i] = *(short8*)&As[(row * 4 + (quad ^ ((row >> 1) & 3))) * 8];
    }
#pragma unroll
    for (int i = 0; i < 4; i++) {
      int row = wn + i * 16 + l16;
      bfr[i] = *(short8*)&Bs[(row * 4 + (quad ^ ((row >> 1) & 3))) * 8];
    }
#pragma unroll
    for (int mi = 0; mi < 4; mi++)
#pragma unroll
      for (int ni = 0; ni < 4; ni++)
        acc[mi][ni] = mfma16(af[mi], bfr[ni], acc[mi][ni]);
    __syncthreads();
  }

  const int mode = (opmode == 1) ? 3 : ((int)blockIdx.z == 2 ? 2 : 0);
  if (mode == 3) {
#pragma unroll
    for (int mi = 0; mi < 4; mi++) {
      int m = m0 + wm + mi * 16 + quad * 4;
#pragma unroll
      for (int ni = 0; ni < 4; ni++) {
        int n = n0 + wn + ni * 16 + l16;
#pragma unroll
        for (int r = 0; r < 4; r++)
          oO[(size_t)(m + r) * DM + n] = acc[mi][ni][r];
      }
    }
  } else if (mode == 2) {
#pragma unroll
    for (int mi = 0; mi < 4; mi++) {
      int m = m0 + wm + mi * 16 + quad * 4;
      int b = m >> 11, s = m & (S - 1);
#pragma unroll
      for (int ni = 0; ni < 4; ni++) {
        int f = n0 + wn + ni * 16 + l16;
        int h = f >> 7, dh = f & (DH - 1);
        union { u16 u[4]; uint2 p; } pk;
#pragma unroll
        for (int r = 0; r < 4; r++) pk.u[r] = f2bf(acc[mi][ni][r]);
        *(uint2*)&oV[((size_t)(b * NH + h) * DH + dh) * S + s] = pk.p;
      }
    }
  } else {
    // RoPE fused; for Q (z==0) also fold 1/sqrt(dk)*log2(e) into the value
    u16* Out = ((int)blockIdx.z == 0) ? oQ : oK;
    const float qs = ((int)blockIdx.z == 0) ? 0.12752780f : 1.0f;
#pragma unroll
    for (int mi = 0; mi < 4; mi++) {
#pragma unroll
      for (int r = 0; r < 4; r++) {
        int m = m0 + wm + mi * 16 + quad * 4 + r;
        int b = m >> 11, s = m & (S - 1);
        int ps = tp[s];
#pragma unroll
        for (int ni = 0; ni < 4; ni++) {
          int f = n0 + wn + ni * 16 + l16;
          int h = f >> 7, dh = f & (DH - 1);
          float own = acc[mi][ni][r];
          float oth = __shfl_xor(own, 1, 64);
          float fr = __expf((float)(dh & ~1) * (-9.210340371976184f / 128.0f));
          float ang = (float)ps * fr;
          float sn, cs; __sincosf(ang, &sn, &cs);
          float res = (dh & 1) ? (oth * sn + own * cs) : (own * cs - oth * sn);
          Out[((size_t)(b * NH + h) * S + s) * DH + dh] = f2bf(res * qs);
        }
      }
    }
  }
}

// ---------- causal flash attention v3: block-coop LDS staging ----------
// Block = 64 q rows (4 waves x 16). K tile 64x128 and V^T tile 128x64 staged
// via global_load_lds into XOR-swizzled LDS, shared by all 4 waves.
// Grid = 1024 blocks, one 64-row group each, biggest group first (LPT).
__global__ __launch_bounds__(256, 3)
void attn_k(const u16* __restrict__ Q, const u16* __restrict__ K,
            const u16* __restrict__ Vt, u16* __restrict__ O)
{
  __shared__ u16 Ks[64 * 128];   // key-major, swizzle: unit r*16 + (c ^ (r&15))
  __shared__ u16 Vs[128 * 64];   // dh-major,  swizzle: unit r*8  + (c ^ (r&7))
  __shared__ u16 P[4][16 * 72];
  const int t = threadIdx.x, w = t >> 6, lane = t & 63;
  const int l16 = lane & 15, quad = lane >> 4;
  const int task = blockIdx.x;
  const int bh = task & 31, b = bh >> 4, h = bh & 15;
  const int g = 31 - (task >> 5);        // big groups dispatch first
  const int qg = g * 64;
  const int qt = qg + w * 16;
  const u16* Qb = Q + (size_t)bh * S * DH;
  const u16* Kb = K + (size_t)bh * S * DH;
  const u16* Vb = Vt + (size_t)bh * DH * S;
  u16* Pw = P[w];

  // staging precompute: K -> wave w rows w*16..+15 (4 instrs x 4 rows);
  //                     V -> wave w rows w*32..+31 (4 instrs x 8 rows)
  const u16* pK[4]; u16* lK[4];
  const u16* pV[4]; u16* lV[4];
#pragma unroll
  for (int j = 0; j < 4; j++) {
    int kr = w * 16 + j * 4 + (lane >> 4);
    int ks = lane & 15;
    int kc = ks ^ (kr & 15);
    pK[j] = Kb + (size_t)kr * DH + kc * 8;
    lK[j] = &Ks[kr * 128 + ks * 8];
    int vr = w * 32 + j * 8 + (lane >> 3);
    int vs = lane & 7;
    int vc = vs ^ (vr & 7);
    pV[j] = Vb + (size_t)vr * S + vc * 8;
    lV[j] = &Vs[vr * 64 + vs * 8];
  }

  short8 aq[4];
#pragma unroll
  for (int kc = 0; kc < 4; kc++)
    aq[kc] = *(const short8*)&Qb[(size_t)(qt + l16) * DH + kc * 32 + quad * 8];

  floatx4 o[8] = {};
  float m_ = -3.0e38f, l_ = 0.0f;
  const int kend = qg + 64;

  for (int k0 = 0; k0 < kend; k0 += 64) {
#pragma unroll
    for (int j = 0; j < 4; j++) async_cp16(pK[j] + (size_t)k0 * DH, lK[j]);
#pragma unroll
    for (int j = 0; j < 4; j++) async_cp16(pV[j] + k0, lV[j]);
    __syncthreads();

    // ---- S^T = K·Q^T : sc[hh] row = key k0+hh*16+quad*4+r, col = q = l16
    floatx4 sc[4] = {};
#pragma unroll
    for (int hh = 0; hh < 4; hh++) {
      int row = hh * 16 + l16;
#pragma unroll
      for (int kc = 0; kc < 4; kc++) {
        short8 kf = *(short8*)&Ks[row * 128 + (((kc * 4 + quad) ^ l16) << 3)];
        sc[hh] = mfma16(kf, aq[kc], sc[hh]);
      }
    }
    // ---- causal mask: only the last tile overlaps the diagonal
    if (k0 + 64 > qt) {
#pragma unroll
      for (int hh = 0; hh < 4; hh++)
#pragma unroll
        for (int r = 0; r < 4; r++) {
          int j = k0 + hh * 16 + quad * 4 + r;
          if (j > qt + l16) sc[hh][r] = -3.0e38f;
        }
    }
    // ---- online softmax, per-lane scalar state (q = l16)
    float mloc = -3.0e38f;
#pragma unroll
    for (int hh = 0; hh < 4; hh++) {
      float a0 = fmaxf(sc[hh][0], sc[hh][1]);
      float a1 = fmaxf(sc[hh][2], sc[hh][3]);
      mloc = fmaxf(mloc, fmaxf(a0, a1));
    }
    mloc = fmaxf(mloc, __shfl_xor(mloc, 16, 64));
    mloc = fmaxf(mloc, __shfl_xor(mloc, 32, 64));
    float nm = fmaxf(m_, mloc);
    float al = __builtin_amdgcn_exp2f(m_ - nm);
    m_ = nm;
    float sloc = 0.0f;
    uint2 pk[4];
#pragma unroll
    for (int hh = 0; hh < 4; hh++) {
      float e0 = __builtin_amdgcn_exp2f(sc[hh][0] - nm);
      float e1 = __builtin_amdgcn_exp2f(sc[hh][1] - nm);
      float e2 = __builtin_amdgcn_exp2f(sc[hh][2] - nm);
      float e3 = __builtin_amdgcn_exp2f(sc[hh][3] - nm);
      sloc += (e0 + e1) + (e2 + e3);
      pk[hh].x = pack2(e0, e1);
      pk[hh].y = pack2(e2, e3);
    }
    float ts = sloc + __shfl_xor(sloc, 16, 64);
    ts += __shfl_xor(ts, 32, 64);
    l_ = l_ * al + ts;
#pragma unroll
    for (int t8 = 0; t8 < 8; t8++)
#pragma unroll
      for (int r = 0; r < 4; r++) o[t8][r] *= al;
    // ---- P^T relayout (per-wave private LDS)
#pragma unroll
    for (int hh = 0; hh < 4; hh++)
      *(uint2*)&Pw[l16 * 72 + hh * 16 + quad * 4] = pk[hh];
    asm volatile("s_waitcnt lgkmcnt(0)" ::: "memory");
    // ---- O^T += V^T · P^T
#pragma unroll
    for (int c = 0; c < 2; c++) {
      short8 pf = *(short8*)&Pw[l16 * 72 + c * 32 + quad * 8];
#pragma unroll
      for (int t8 = 0; t8 < 8; t8++) {
        int row = t8 * 16 + l16;
        short8 av = *(short8*)&Vs[row * 64 + (((c * 4 + quad) ^ (l16 & 7)) << 3)];
        o[t8] = mfma16(av, pf, o[t8]);
      }
    }
    __syncthreads();
  }

  // ---- epilogue: lane's q-row = qt+l16, dh = t8*16 + quad*4 + r
  float inv = __builtin_amdgcn_rcpf(l_);
#pragma unroll
  for (int t8 = 0; t8 < 8; t8++) {
    union { u16 u[4]; uint2 p; } pk;
#pragma unroll
    for (int r = 0; r < 4; r++) pk.u[r] = f2bf(o[t8][r] * inv);
    *(uint2*)&O[((size_t)(b * S + qt + l16)) * DM + h * DH + t8 * 16 + quad * 4] = pk.p;
  }
}

extern "C" void kernel_launch(void* const* d_in, const int* in_sizes, int n_in,
                              void* d_out, int out_size, void* d_ws, size_t ws_size,
                              hipStream_t stream) {
  const float* x  = (const float*)d_in[0];
  const float* Wq = (const float*)d_in[1];
  const float* Wk = (const float*)d_in[2];
  const float* Wv = (const float*)d_in[3];
  const float* Wo = (const float*)d_in[4];
  const int*   tp = (const int*)d_in[5];

  char* ws = (char*)d_ws;
  u16* Wt = (u16*)ws;
  u16* xb = (u16*)(ws + 33554432);
  u16* Qb = (u16*)(ws + 50331648);
  u16* Kb = (u16*)(ws + 67108864);
  u16* Vb = (u16*)(ws + 83886080);
  u16* Ob = (u16*)(ws + 100663296);

  conv_x_k<<<8192, 256, 0, stream>>>(x, xb);
  conv_w_k<<<dim3(64, 64, 4), 256, 0, stream>>>(Wq, Wk, Wv, Wo, Wt);
  gemm_k<<<dim3(16, 32, 3), 256, 0, stream>>>(xb, Wt, Qb, Kb, Vb, nullptr, tp, 0);
  attn_k<<<1024, 256, 0, stream>>>(Qb, Kb, Vb, Ob);
  gemm_k<<<dim3(16, 32, 1), 256, 0, stream>>>(Ob, Wt, nullptr, nullptr, nullptr,
                                              (float*)d_out, tp, 1);
}